// Round 3
// baseline (1295.670 us; speedup 1.0000x reference)
//
#include <hip/hip_runtime.h>
#include <stdint.h>
#include <math.h>

typedef unsigned short u16;
typedef unsigned int u32;

#define HID   768
#define TGT   20
#define LBL   30522
#define RPAIR 512
#define ROWS  10240          // RPAIR * TGT
#define KCAT  1536           // 2*HID (lh|rh)
#define NPAD2 30720          // 120 * 256  (LBL padded to 256-tile multiple)

typedef float  f32x4  __attribute__((ext_vector_type(4)));
typedef __bf16 bf16x8 __attribute__((ext_vector_type(8)));

__device__ __forceinline__ u16 f2bf(float f) {
  u32 u = __float_as_uint(f);
  u += 0x7fffu + ((u >> 16) & 1u);          // RNE
  return (u16)(u >> 16);
}
__device__ __forceinline__ float bf2f(u16 h) {
  return __uint_as_float(((u32)h) << 16);
}
__device__ __forceinline__ float gelu_tanh(float x) {
  float x3 = x * x * x;
  float t = tanhf(0.7978845608028654f * (x + 0.044715f * x3));
  return 0.5f * x * (1.0f + t);
}

// async global->LDS, 16B per lane; lds dst wave-uniform base (HW adds lane*16)
__device__ __forceinline__ void async16(u16* lds, const u16* g) {
  __builtin_amdgcn_global_load_lds(
      (__attribute__((address_space(1))) void*)const_cast<u16*>(g),
      (__attribute__((address_space(3))) void*)lds,
      16, 0, 0);
}

#define BARRIER() do { asm volatile("" ::: "memory"); __builtin_amdgcn_s_barrier(); asm volatile("" ::: "memory"); } while (0)

// ---------------------------------------------------------------------------
// Transpose + f32->bf16:  B[K][N] f32  ->  Bt[Npad][K] bf16 (pad rows zeroed)
// ---------------------------------------------------------------------------
__global__ __launch_bounds__(256) void tconv_kernel(const float* __restrict__ B,
                                                    u16* __restrict__ Bt,
                                                    int K, int N, int Npad) {
  __shared__ u16 tile[32][34];
  int n0 = blockIdx.x * 32, k0 = blockIdx.y * 32;
  int tx = threadIdx.x & 31, ty = threadIdx.x >> 5;
#pragma unroll
  for (int i = 0; i < 4; i++) {
    int kk = ty + i * 8;
    int k = k0 + kk, n = n0 + tx;
    float v = (k < K && n < N) ? B[(size_t)k * N + n] : 0.0f;
    tile[kk][tx] = f2bf(v);
  }
  __syncthreads();
#pragma unroll
  for (int i = 0; i < 4; i++) {
    int nn = ty + i * 8;
    int n = n0 + nn, k = k0 + tx;
    if (n < Npad && k < K) Bt[(size_t)n * K + k] = tile[tx][nn];
  }
}

// ---------------------------------------------------------------------------
// Gather pair rows -> A1[512][1536] bf16
// ---------------------------------------------------------------------------
__global__ __launch_bounds__(256) void gather_kernel(const float* __restrict__ nodes,
                                                     const int* __restrict__ p32,
                                                     u16* __restrict__ A1) {
  int idx = blockIdx.x * 256 + threadIdx.x;
  if (idx >= RPAIR * KCAT) return;
  bool is64 = ((p32[1] | p32[3] | p32[5] | p32[7] | p32[9] | p32[11] | p32[13] | p32[15]) == 0);
  int r = idx / KCAT, c = idx - r * KCAT;
  int b = r >> 7, p = r & 127;
  int which = (c >= HID) ? 1 : 0;
  int cc = which ? (c - HID) : c;          // HID=768 is NOT pow2
  int slot = (b * 128 + p) * 2 + which;
  int node = (is64 ? p32[slot * 2] : p32[slot]) + 1;
  float v = nodes[((size_t)(b * 512 + node)) * HID + cc];
  A1[idx] = f2bf(v);
}

// ---------------------------------------------------------------------------
// pe_proj[t][j] = pos_emb[t] @ W1[1536:2304] + b1     (20 x 768)
// ---------------------------------------------------------------------------
__global__ __launch_bounds__(256) void peproj_kernel(const float* __restrict__ pos_emb,
                                                     const float* __restrict__ W1,
                                                     const float* __restrict__ b1,
                                                     float* __restrict__ pep) {
  __shared__ float pe[HID];
  int t = blockIdx.x, tid = threadIdx.x;
  for (int i = tid; i < HID; i += 256) pe[i] = pos_emb[t * HID + i];
  __syncthreads();
  float acc0 = 0.f, acc1 = 0.f, acc2 = 0.f;
  const float* Wp = W1 + (size_t)KCAT * HID;
  for (int k = 0; k < HID; k++) {
    float p = pe[k];
    const float* wr = Wp + (size_t)k * HID;
    acc0 = fmaf(p, wr[tid], acc0);
    acc1 = fmaf(p, wr[tid + 256], acc1);
    acc2 = fmaf(p, wr[tid + 512], acc2);
  }
  pep[t * HID + tid]       = acc0 + b1[tid];
  pep[t * HID + tid + 256] = acc1 + b1[tid + 256];
  pep[t * HID + tid + 512] = acc2 + b1[tid + 512];
}

// ---------------------------------------------------------------------------
// 128x128 MFMA GEMM (m97 structure) for the two small layers
// EPI 0: C f32 plain   EPI 1: C bf16 = bf16(gelu(acc+bias))
// ---------------------------------------------------------------------------
template <int EPI>
__global__ __launch_bounds__(256) void gemm_bt(const u16* __restrict__ A,
                                               const u16* __restrict__ Bt,
                                               const float* __restrict__ bias,
                                               float* __restrict__ Cf,
                                               u16* __restrict__ Cb,
                                               int N, int K) {
  __shared__ __align__(16) u16 As[128 * 32];
  __shared__ __align__(16) u16 Bs[128 * 32];
  const int tid  = threadIdx.x;
  const int lane = tid & 63;
  const int w    = tid >> 6;
  const int wr   = w >> 1, wc = w & 1;
  const int m0 = blockIdx.y * 128;
  const int n0 = blockIdx.x * 128;

  f32x4 acc[4][4];
  const f32x4 fzero = {0.f, 0.f, 0.f, 0.f};
#pragma unroll
  for (int m = 0; m < 4; m++)
#pragma unroll
    for (int n = 0; n < 4; n++) acc[m][n] = fzero;

  const int srow = lane >> 2;
  const int scol = (lane & 3) * 8;
  const int nkt = K >> 5;

  for (int kt = 0; kt < nkt; ++kt) {
    const int k0 = kt << 5;
#pragma unroll
    for (int j = 0; j < 2; j++) {
      int rbase = w * 32 + j * 16;
      async16(&As[rbase * 32], A + (size_t)(m0 + rbase + srow) * K + k0 + scol);
      async16(&Bs[rbase * 32], Bt + (size_t)(n0 + rbase + srow) * K + k0 + scol);
    }
    asm volatile("s_waitcnt vmcnt(0)" ::: "memory");
    __syncthreads();

    bf16x8 a[4], b[4];
    const int kk = (lane >> 4) * 8;
#pragma unroll
    for (int m = 0; m < 4; m++)
      a[m] = *reinterpret_cast<const bf16x8*>(&As[(wr * 64 + m * 16 + (lane & 15)) * 32 + kk]);
#pragma unroll
    for (int n = 0; n < 4; n++)
      b[n] = *reinterpret_cast<const bf16x8*>(&Bs[(wc * 64 + n * 16 + (lane & 15)) * 32 + kk]);
#pragma unroll
    for (int m = 0; m < 4; m++)
#pragma unroll
      for (int n = 0; n < 4; n++)
        acc[m][n] = __builtin_amdgcn_mfma_f32_16x16x32_bf16(a[m], b[n], acc[m][n], 0, 0, 0);
    __syncthreads();
  }

  const int rr = (lane >> 4) * 4;
  const int cc = lane & 15;
#pragma unroll
  for (int m = 0; m < 4; m++) {
#pragma unroll
    for (int n = 0; n < 4; n++) {
      int col = n0 + wc * 64 + n * 16 + cc;
#pragma unroll
      for (int j = 0; j < 4; j++) {
        int row = m0 + wr * 64 + m * 16 + rr + j;
        float v = acc[m][n][j];
        if (EPI == 0) {
          Cf[(size_t)row * N + col] = v;
        } else {
          v = gelu_tanh(v + bias[col]);
          Cb[(size_t)row * N + col] = f2bf(v);
        }
      }
    }
  }
}

// ---------------------------------------------------------------------------
// Head GEMM: 256x256 tile, BK=64, 8 waves (2Mx4N), 8-phase schedule.
// A[10240][768] bf16, B = WdT[30720][768] bf16, C f32 [10240][30522] (+bd, col guard)
// LDS: As[2][256][64] + Bs[2][256][64] = 128 KiB, XOR chunk-swizzle (chunk ^= row&7).
// Per K-tile: 4 phases x {ds_read quadrant frags, stage 1 half-tile (2 gload_lds),
//   bar, lgkm(0), setprio(1), 16 MFMA, setprio(0), bar}; boundary vmcnt(4).
// Stagger: tile t phases stage {t+1.Bh0, t+1.Bh1, t+2.Ah0, t+2.Ah1}; A-halves of
// the CURRENT buffer are dead after phase 1's end-barrier (all A reads done), so
// t+2's A can overwrite them at phases 2/3.
// ---------------------------------------------------------------------------
__global__ __launch_bounds__(512, 2) void gemm256_head(const u16* __restrict__ A,
                                                       const u16* __restrict__ B,
                                                       const float* __restrict__ bias,
                                                       float* __restrict__ C) {
  __shared__ __align__(16) u16 As[2][256 * 64];
  __shared__ __align__(16) u16 Bs[2][256 * 64];
  const int tid  = threadIdx.x;
  const int lane = tid & 63;
  const int wid  = tid >> 6;           // 0..7
  const int wm   = wid >> 2;           // 0..1
  const int wn   = wid & 3;            // 0..3

  // T1: bijective XCD swizzle, grid = 40*120 = 4800 (4800 % 8 == 0), m-major
  int orig = blockIdx.x;
  int l = (orig & 7) * 600 + (orig >> 3);
  int mt = l / 120, nt = l - mt * 120;
  const int m0 = mt * 256, n0 = nt * 256;
  const int nkt = 12;                  // 768 / 64

  f32x4 acc[8][4];
  const f32x4 fzero = {0.f, 0.f, 0.f, 0.f};
#pragma unroll
  for (int mi = 0; mi < 8; mi++)
#pragma unroll
    for (int ni = 0; ni < 4; ni++) acc[mi][ni] = fzero;

  // stage one half-tile (128 rows x 64 K) of src into ldsReg (row0 of a 256-row region).
  // Pre-swizzled global source: LDS[row][c'] = G[row][c' ^ (row&7)]  (16B chunks).
  const int sl_r = lane >> 3;          // 0..7: row within 8-row stripe
  const int sl_c = ((lane & 7) ^ sl_r) * 8;  // swizzled k-elem offset
  auto stage_half = [&](const u16* src, int grow0, u16* ldsReg, int half, int ke0) {
#pragma unroll
    for (int j = 0; j < 2; j++) {
      int rowb = half * 128 + (j * 8 + wid) * 8;           // wave-uniform
      const u16* gp = src + (size_t)(grow0 + rowb + sl_r) * 768 + ke0 + sl_c;
      async16(ldsReg + rowb * 64, gp);
    }
  };
  // swizzled ds_read of one bf16x8 fragment
  auto lda = [&](const u16* buf, int mi, int ks) -> bf16x8 {
    int row = wm * 128 + mi * 16 + (lane & 15);
    int kch = ks * 4 + (lane >> 4);
    return *reinterpret_cast<const bf16x8*>(&buf[row * 64 + ((kch ^ (row & 7)) << 3)]);
  };
  auto ldb = [&](const u16* buf, int ni, int ks) -> bf16x8 {
    int row = wn * 64 + ni * 16 + (lane & 15);
    int kch = ks * 4 + (lane >> 4);
    return *reinterpret_cast<const bf16x8*>(&buf[row * 64 + ((kch ^ (row & 7)) << 3)]);
  };

  // prologue: tile0 fully + tile1 A-halves; wait so tile0 landed (4 loads in flight)
  stage_half(A, m0, As[0], 0, 0);
  stage_half(A, m0, As[0], 1, 0);
  stage_half(B, n0, Bs[0], 0, 0);
  stage_half(B, n0, Bs[0], 1, 0);
  stage_half(A, m0, As[1], 0, 64);
  stage_half(A, m0, As[1], 1, 64);
  asm volatile("s_waitcnt vmcnt(4)" ::: "memory");
  __builtin_amdgcn_sched_barrier(0);
  __builtin_amdgcn_s_barrier();
  asm volatile("" ::: "memory");

  bf16x8 aF[8][2];
  bf16x8 bF[4][2];

#define MFMA_QUAD(MI0, NI0)                                                        \
  do {                                                                             \
    __builtin_amdgcn_s_setprio(1);                                                 \
    _Pragma("unroll") for (int mi = (MI0); mi < (MI0) + 4; ++mi)                   \
      _Pragma("unroll") for (int ni = (NI0); ni < (NI0) + 2; ++ni)                 \
        _Pragma("unroll") for (int ks = 0; ks < 2; ++ks)                           \
          acc[mi][ni] = __builtin_amdgcn_mfma_f32_16x16x32_bf16(aF[mi][ks], bF[ni][ks], acc[mi][ni], 0, 0, 0); \
    __builtin_amdgcn_s_setprio(0);                                                 \
  } while (0)

#define WAIT_LGKM() do { asm volatile("s_waitcnt lgkmcnt(0)" ::: "memory"); __builtin_amdgcn_sched_barrier(0); } while (0)

  for (int t = 0; t < nkt; ++t) {
    const u16* Ab = As[t & 1];
    const u16* Bb = Bs[t & 1];
    u16* Bnext = Bs[(t + 1) & 1];
    u16* Acur  = As[t & 1];            // t+2's A goes into current (dead) A region
    const int ke1 = (t + 1) * 64, ke2 = (t + 2) * 64;
    const bool sB = (t + 1) < nkt, sA = (t + 2) < nkt;

    // ---- phase 0: Q0 (mi 0-3, ni 0-1) ----
#pragma unroll
    for (int mi = 0; mi < 4; ++mi)
#pragma unroll
      for (int ks = 0; ks < 2; ++ks) aF[mi][ks] = lda(Ab, mi, ks);
#pragma unroll
    for (int ni = 0; ni < 2; ++ni)
#pragma unroll
      for (int ks = 0; ks < 2; ++ks) bF[ni][ks] = ldb(Bb, ni, ks);
    if (sB) stage_half(B, n0, Bnext, 0, ke1);
    BARRIER();
    WAIT_LGKM();
    MFMA_QUAD(0, 0);
    BARRIER();

    // ---- phase 1: Q1 (mi 4-7, ni 0-1) ----
#pragma unroll
    for (int mi = 4; mi < 8; ++mi)
#pragma unroll
      for (int ks = 0; ks < 2; ++ks) aF[mi][ks] = lda(Ab, mi, ks);
    if (sB) stage_half(B, n0, Bnext, 1, ke1);
    BARRIER();
    WAIT_LGKM();
    MFMA_QUAD(4, 0);
    BARRIER();   // after this barrier all A-reads of tile t are complete

    // ---- phase 2: Q3 (mi 4-7, ni 2-3) ----
#pragma unroll
    for (int ni = 2; ni < 4; ++ni)
#pragma unroll
      for (int ks = 0; ks < 2; ++ks) bF[ni][ks] = ldb(Bb, ni, ks);
    if (sA) stage_half(A, m0, Acur, 0, ke2);
    BARRIER();
    WAIT_LGKM();
    MFMA_QUAD(4, 2);
    BARRIER();

    // ---- phase 3: Q2 (mi 0-3, ni 2-3) ----
    if (sA) stage_half(A, m0, Acur, 1, ke2);
    BARRIER();
    MFMA_QUAD(0, 2);
    // boundary: ensure all of tile t+1 is in LDS; keep t+2's A stages in flight
    if (t + 2 < nkt) {
      asm volatile("s_waitcnt vmcnt(4)" ::: "memory");
    } else if (t + 1 < nkt) {
      asm volatile("s_waitcnt vmcnt(0)" ::: "memory");
    }
    __builtin_amdgcn_sched_barrier(0);
    BARRIER();
  }
#undef MFMA_QUAD
#undef WAIT_LGKM

  // epilogue: D layout col = lane&15, row = (lane>>4)*4 + j
  const int r0 = m0 + wm * 128;
  const int c0 = n0 + wn * 64;
  const int rr = (lane >> 4) * 4;
  const int ccl = lane & 15;
#pragma unroll
  for (int ni = 0; ni < 4; ++ni) {
    int col = c0 + ni * 16 + ccl;
    if (col < LBL) {
      float bv = bias[col];
#pragma unroll
      for (int mi = 0; mi < 8; ++mi)
#pragma unroll
        for (int j = 0; j < 4; ++j) {
          int row = r0 + mi * 16 + rr + j;
          C[(size_t)row * LBL + col] = acc[mi][ni][j] + bv;
        }
    }
  }
}

// ---------------------------------------------------------------------------
// fuse1: h1[g] = bf16( LN( gelu( s[r] + pep[t] ) ) * g1 + be1 ),  g = r*20+t
// ---------------------------------------------------------------------------
__global__ __launch_bounds__(256) void fuse1_kernel(const float* __restrict__ s,
                                                    const float* __restrict__ pep,
                                                    const float* __restrict__ g1,
                                                    const float* __restrict__ be1,
                                                    u16* __restrict__ h1) {
  __shared__ float red[8];
  int g = blockIdx.x, tid = threadIdx.x;
  int r = g / TGT, t = g - r * TGT;
  const float* sr = s + (size_t)r * HID;
  const float* pt = pep + (size_t)t * HID;
  float y[3], s1 = 0.f, s2 = 0.f;
#pragma unroll
  for (int i = 0; i < 3; i++) {
    int j = tid + i * 256;
    float x = sr[j] + pt[j];
    y[i] = gelu_tanh(x);
    s1 += y[i];
    s2 += y[i] * y[i];
  }
#pragma unroll
  for (int off = 32; off > 0; off >>= 1) {
    s1 += __shfl_down(s1, off);
    s2 += __shfl_down(s2, off);
  }
  if ((tid & 63) == 0) { red[tid >> 6] = s1; red[4 + (tid >> 6)] = s2; }
  __syncthreads();
  float mean = (red[0] + red[1] + red[2] + red[3]) * (1.0f / HID);
  float var  = (red[4] + red[5] + red[6] + red[7]) * (1.0f / HID) - mean * mean;
  float inv  = rsqrtf(var + 1e-5f);
#pragma unroll
  for (int i = 0; i < 3; i++) {
    int j = tid + i * 256;
    h1[(size_t)g * HID + j] = f2bf((y[i] - mean) * inv * g1[j] + be1[j]);
  }
}

// ---------------------------------------------------------------------------
// fuse2: h2[g] = bf16( LN( G[g] ) * g2 + be2 ) — safe in-place (G == h2)
// ---------------------------------------------------------------------------
__global__ __launch_bounds__(256) void fuse2_kernel(const u16* __restrict__ G,
                                                    const float* __restrict__ g2,
                                                    const float* __restrict__ be2,
                                                    u16* __restrict__ h2) {
  __shared__ float red[8];
  int g = blockIdx.x, tid = threadIdx.x;
  const u16* gr = G + (size_t)g * HID;
  float y[3], s1 = 0.f, s2 = 0.f;
#pragma unroll
  for (int i = 0; i < 3; i++) {
    int j = tid + i * 256;
    y[i] = bf2f(gr[j]);
    s1 += y[i];
    s2 += y[i] * y[i];
  }
#pragma unroll
  for (int off = 32; off > 0; off >>= 1) {
    s1 += __shfl_down(s1, off);
    s2 += __shfl_down(s2, off);
  }
  if ((tid & 63) == 0) { red[tid >> 6] = s1; red[4 + (tid >> 6)] = s2; }
  __syncthreads();
  float mean = (red[0] + red[1] + red[2] + red[3]) * (1.0f / HID);
  float var  = (red[4] + red[5] + red[6] + red[7]) * (1.0f / HID) - mean * mean;
  float inv  = rsqrtf(var + 1e-5f);
#pragma unroll
  for (int i = 0; i < 3; i++) {
    int j = tid + i * 256;
    h2[(size_t)g * HID + j] = f2bf((y[i] - mean) * inv * g2[j] + be2[j]);
  }
}

// ---------------------------------------------------------------------------
extern "C" void kernel_launch(void* const* d_in, const int* in_sizes, int n_in,
                              void* d_out, int out_size, void* d_ws, size_t ws_size,
                              hipStream_t stream) {
  const float* input_nodes = (const float*)d_in[0];
  const int*   pairs       = (const int*)d_in[1];
  const float* pos_emb     = (const float*)d_in[2];
  const float* W1  = (const float*)d_in[3];
  const float* b1  = (const float*)d_in[4];
  const float* g1  = (const float*)d_in[5];
  const float* be1 = (const float*)d_in[6];
  const float* W2  = (const float*)d_in[7];
  const float* b2  = (const float*)d_in[8];
  const float* g2  = (const float*)d_in[9];
  const float* be2 = (const float*)d_in[10];
  const float* Wd  = (const float*)d_in[11];
  const float* bd  = (const float*)d_in[12];
  float* out = (float*)d_out;

  char* ws = (char*)d_ws;
  u16*   WdT   = (u16*)(ws + 0);                 // 30720*768*2 = 47,185,920
  u16*   W2T   = (u16*)(ws + 47185920);          // 1,179,648
  u16*   W1lrT = (u16*)(ws + 48365568);          // 2,359,296
  u16*   A1    = (u16*)(ws + 50724864);          // 1,572,864
  float* pep   = (float*)(ws + 52297728);        // 61,440
  float* sbuf  = (float*)(ws + 52359168);        // 1,572,864
  u16*   h1    = (u16*)(ws + 53932032);          // 15,728,640
  u16*   G     = (u16*)(ws + 69660672);          // 15,728,640 -> end 85,389,312 (h2 in-place in G)

  // weight prep (bf16, B^T layouts)
  tconv_kernel<<<dim3(960, 24), 256, 0, stream>>>(Wd, WdT, HID, LBL, NPAD2);
  tconv_kernel<<<dim3(24, 24), 256, 0, stream>>>(W2, W2T, HID, HID, HID);
  tconv_kernel<<<dim3(24, 48), 256, 0, stream>>>(W1, W1lrT, KCAT, HID, HID);
  gather_kernel<<<dim3((RPAIR * KCAT + 255) / 256), 256, 0, stream>>>(input_nodes, pairs, A1);
  peproj_kernel<<<dim3(TGT), 256, 0, stream>>>(pos_emb, W1, b1, pep);

  // layer 1: s = [lh|rh] @ W1[0:1536]   (512 x 768)
  gemm_bt<0><<<dim3(6, 4), 256, 0, stream>>>(A1, W1lrT, nullptr, sbuf, nullptr, HID, KCAT);
  fuse1_kernel<<<dim3(ROWS), 256, 0, stream>>>(sbuf, pep, g1, be1, h1);

  // layer 2: G = gelu(h1 @ W2 + b2); h2 = LN(G) in-place
  gemm_bt<1><<<dim3(6, 80), 256, 0, stream>>>(h1, W2T, b2, nullptr, G, HID, HID);
  fuse2_kernel<<<dim3(ROWS), 256, 0, stream>>>(G, g2, be2, G);

  // head: out = h2 @ Wd + bd   (10240 x 30522), 256^2 8-phase
  gemm256_head<<<dim3(4800), 512, 0, stream>>>(G, WdT, bd, out);
}

// Round 4
// 1286.833 us; speedup vs baseline: 1.0069x; 1.0069x over previous
//
#include <hip/hip_runtime.h>
#include <stdint.h>
#include <math.h>

typedef unsigned short u16;
typedef unsigned int u32;

#define HID   768
#define TGT   20
#define LBL   30522
#define RPAIR 512
#define ROWS  10240          // RPAIR * TGT
#define KCAT  1536           // 2*HID (lh|rh)
#define NPAD  30592          // 239 * 128  (LBL padded to 128-tile multiple)

typedef float  f32x4  __attribute__((ext_vector_type(4)));
typedef __bf16 bf16x8 __attribute__((ext_vector_type(8)));

__device__ __forceinline__ u16 f2bf(float f) {
  u32 u = __float_as_uint(f);
  u += 0x7fffu + ((u >> 16) & 1u);          // RNE
  return (u16)(u >> 16);
}
__device__ __forceinline__ float bf2f(u16 h) {
  return __uint_as_float(((u32)h) << 16);
}
__device__ __forceinline__ float gelu_tanh(float x) {
  float x3 = x * x * x;
  float t = tanhf(0.7978845608028654f * (x + 0.044715f * x3));
  return 0.5f * x * (1.0f + t);
}

// async global->LDS, 16B per lane; lds dst wave-uniform base (HW adds lane*16)
__device__ __forceinline__ void async16(u16* lds, const u16* g) {
  __builtin_amdgcn_global_load_lds(
      (__attribute__((address_space(1))) void*)const_cast<u16*>(g),
      (__attribute__((address_space(3))) void*)lds,
      16, 0, 0);
}

// ---------------------------------------------------------------------------
// Transpose + f32->bf16:  B[K][N] f32  ->  Bt[Npad][K] bf16 (pad rows zeroed)
// ---------------------------------------------------------------------------
__global__ __launch_bounds__(256) void tconv_kernel(const float* __restrict__ B,
                                                    u16* __restrict__ Bt,
                                                    int K, int N, int Npad) {
  __shared__ u16 tile[32][34];
  int n0 = blockIdx.x * 32, k0 = blockIdx.y * 32;
  int tx = threadIdx.x & 31, ty = threadIdx.x >> 5;
#pragma unroll
  for (int i = 0; i < 4; i++) {
    int kk = ty + i * 8;
    int k = k0 + kk, n = n0 + tx;
    float v = (k < K && n < N) ? B[(size_t)k * N + n] : 0.0f;
    tile[kk][tx] = f2bf(v);
  }
  __syncthreads();
#pragma unroll
  for (int i = 0; i < 4; i++) {
    int nn = ty + i * 8;
    int n = n0 + nn, k = k0 + tx;
    if (n < Npad && k < K) Bt[(size_t)n * K + k] = tile[tx][nn];
  }
}

// ---------------------------------------------------------------------------
// Gather pair rows -> A1[512][1536] bf16
// ---------------------------------------------------------------------------
__global__ __launch_bounds__(256) void gather_kernel(const float* __restrict__ nodes,
                                                     const int* __restrict__ p32,
                                                     u16* __restrict__ A1) {
  int idx = blockIdx.x * 256 + threadIdx.x;
  if (idx >= RPAIR * KCAT) return;
  bool is64 = ((p32[1] | p32[3] | p32[5] | p32[7] | p32[9] | p32[11] | p32[13] | p32[15]) == 0);
  int r = idx / KCAT, c = idx - r * KCAT;
  int b = r >> 7, p = r & 127;
  int which = (c >= HID) ? 1 : 0;
  int cc = which ? (c - HID) : c;          // HID=768 is NOT pow2
  int slot = (b * 128 + p) * 2 + which;
  int node = (is64 ? p32[slot * 2] : p32[slot]) + 1;
  float v = nodes[((size_t)(b * 512 + node)) * HID + cc];
  A1[idx] = f2bf(v);
}

// ---------------------------------------------------------------------------
// pe_proj[t][j] = pos_emb[t] @ W1[1536:2304] + b1     (20 x 768)
// ---------------------------------------------------------------------------
__global__ __launch_bounds__(256) void peproj_kernel(const float* __restrict__ pos_emb,
                                                     const float* __restrict__ W1,
                                                     const float* __restrict__ b1,
                                                     float* __restrict__ pep) {
  __shared__ float pe[HID];
  int t = blockIdx.x, tid = threadIdx.x;
  for (int i = tid; i < HID; i += 256) pe[i] = pos_emb[t * HID + i];
  __syncthreads();
  float acc0 = 0.f, acc1 = 0.f, acc2 = 0.f;
  const float* Wp = W1 + (size_t)KCAT * HID;
  for (int k = 0; k < HID; k++) {
    float p = pe[k];
    const float* wr = Wp + (size_t)k * HID;
    acc0 = fmaf(p, wr[tid], acc0);
    acc1 = fmaf(p, wr[tid + 256], acc1);
    acc2 = fmaf(p, wr[tid + 512], acc2);
  }
  pep[t * HID + tid]       = acc0 + b1[tid];
  pep[t * HID + tid + 256] = acc1 + b1[tid + 256];
  pep[t * HID + tid + 512] = acc2 + b1[tid + 512];
}

// ---------------------------------------------------------------------------
// 128x128 MFMA GEMM (m97 structure, BK=32) for the two small layers
// EPI 0: C f32 plain   EPI 1: C bf16 = bf16(gelu(acc+bias))
// ---------------------------------------------------------------------------
template <int EPI>
__global__ __launch_bounds__(256) void gemm_bt(const u16* __restrict__ A,
                                               const u16* __restrict__ Bt,
                                               const float* __restrict__ bias,
                                               float* __restrict__ Cf,
                                               u16* __restrict__ Cb,
                                               int N, int K) {
  __shared__ __align__(16) u16 As[128 * 32];
  __shared__ __align__(16) u16 Bs[128 * 32];
  const int tid  = threadIdx.x;
  const int lane = tid & 63;
  const int w    = tid >> 6;
  const int wr   = w >> 1, wc = w & 1;
  const int m0 = blockIdx.y * 128;
  const int n0 = blockIdx.x * 128;

  f32x4 acc[4][4];
  const f32x4 fzero = {0.f, 0.f, 0.f, 0.f};
#pragma unroll
  for (int m = 0; m < 4; m++)
#pragma unroll
    for (int n = 0; n < 4; n++) acc[m][n] = fzero;

  const int srow = lane >> 2;
  const int scol = (lane & 3) * 8;
  const int nkt = K >> 5;

  for (int kt = 0; kt < nkt; ++kt) {
    const int k0 = kt << 5;
#pragma unroll
    for (int j = 0; j < 2; j++) {
      int rbase = w * 32 + j * 16;
      async16(&As[rbase * 32], A + (size_t)(m0 + rbase + srow) * K + k0 + scol);
      async16(&Bs[rbase * 32], Bt + (size_t)(n0 + rbase + srow) * K + k0 + scol);
    }
    asm volatile("s_waitcnt vmcnt(0)" ::: "memory");
    __syncthreads();

    bf16x8 a[4], b[4];
    const int kk = (lane >> 4) * 8;
#pragma unroll
    for (int m = 0; m < 4; m++)
      a[m] = *reinterpret_cast<const bf16x8*>(&As[(wr * 64 + m * 16 + (lane & 15)) * 32 + kk]);
#pragma unroll
    for (int n = 0; n < 4; n++)
      b[n] = *reinterpret_cast<const bf16x8*>(&Bs[(wc * 64 + n * 16 + (lane & 15)) * 32 + kk]);
#pragma unroll
    for (int m = 0; m < 4; m++)
#pragma unroll
      for (int n = 0; n < 4; n++)
        acc[m][n] = __builtin_amdgcn_mfma_f32_16x16x32_bf16(a[m], b[n], acc[m][n], 0, 0, 0);
    __syncthreads();
  }

  const int rr = (lane >> 4) * 4;
  const int cc = lane & 15;
#pragma unroll
  for (int m = 0; m < 4; m++) {
#pragma unroll
    for (int n = 0; n < 4; n++) {
      int col = n0 + wc * 64 + n * 16 + cc;
#pragma unroll
      for (int j = 0; j < 4; j++) {
        int row = m0 + wr * 64 + m * 16 + rr + j;
        float v = acc[m][n][j];
        if (EPI == 0) {
          Cf[(size_t)row * N + col] = v;
        } else {
          v = gelu_tanh(v + bias[col]);
          Cb[(size_t)row * N + col] = f2bf(v);
        }
      }
    }
  }
}

// ---------------------------------------------------------------------------
// Head GEMM: 128x128 tile, BK=64, 4 waves, double-buffered LDS (64 KiB ->
// 2 blocks/CU), issue-early staging: stage(t+1) BEFORE compute(t), single
// __syncthreads per K-tile (its implicit vmcnt(0) covers the staged loads).
// XCD-chunked raster: xcd = bid&7 owns m-tiles [xcd*10, xcd*10+10); n sweeps
// outer -> A-chunk (10x128x768x2B = 2MB) L2-resident per XCD, Wd panel shared
// across XCDs via LLC (single HBM fetch).
// Chunk-XOR LDS swizzle both-sides (verified numerically in round 3).
// C = A@B^T + bias, f32, col<LBL guard.
// ---------------------------------------------------------------------------
__global__ __launch_bounds__(256) void gemm128_head(const u16* __restrict__ A,
                                                    const u16* __restrict__ B,
                                                    const float* __restrict__ bias,
                                                    float* __restrict__ C) {
  __shared__ __align__(16) u16 As[2][128 * 64];
  __shared__ __align__(16) u16 Bs[2][128 * 64];
  const int tid  = threadIdx.x;
  const int lane = tid & 63;
  const int w    = tid >> 6;      // 0..3
  const int wr   = w >> 1, wc = w & 1;

  // XCD-chunked raster (19120 = 8 * 2390 = 8 * 239 * 10, bijective)
  const int bid   = blockIdx.x;
  const int xcd   = bid & 7;
  const int idx   = bid >> 3;               // 0..2389
  const int ntile = idx / 10;               // 0..238  (outer: n sweeps)
  const int mtile = xcd * 10 + (idx - ntile * 10);   // 0..79
  const int m0 = mtile * 128;
  const int n0 = ntile * 128;

  f32x4 acc[4][4];
  const f32x4 fzero = {0.f, 0.f, 0.f, 0.f};
#pragma unroll
  for (int m = 0; m < 4; m++)
#pragma unroll
    for (int n = 0; n < 4; n++) acc[m][n] = fzero;

  // staging: lane covers row (lane>>3), 16B chunk ((lane&7)^sl_r) of each 8-row stripe
  const int sl_r = lane >> 3;                       // 0..7
  const int sl_c = ((lane & 7) ^ sl_r) * 8;         // pre-swizzled global chunk
  auto stage = [&](int buf, int kt) {
    const int k0 = kt * 64;
#pragma unroll
    for (int j = 0; j < 4; j++) {
      int rbase = w * 32 + j * 8;                   // wave-uniform
      async16(&As[buf][rbase * 64], A + (size_t)(m0 + rbase + sl_r) * 768 + k0 + sl_c);
      async16(&Bs[buf][rbase * 64], B + (size_t)(n0 + rbase + sl_r) * 768 + k0 + sl_c);
    }
  };
  // swizzled ds_read of one bf16x8 fragment
  auto lda = [&](const u16* buf, int m, int ks) -> bf16x8 {
    int row = wr * 64 + m * 16 + (lane & 15);
    int kch = ks * 4 + (lane >> 4);
    return *reinterpret_cast<const bf16x8*>(&buf[row * 64 + ((kch ^ (row & 7)) << 3)]);
  };
  auto ldb = [&](const u16* buf, int n, int ks) -> bf16x8 {
    int row = wc * 64 + n * 16 + (lane & 15);
    int kch = ks * 4 + (lane >> 4);
    return *reinterpret_cast<const bf16x8*>(&buf[row * 64 + ((kch ^ (row & 7)) << 3)]);
  };

  const int nkt = 12;                               // 768 / 64
  stage(0, 0);
  __syncthreads();                                  // drains vmcnt(0) + barrier

  for (int t = 0; t < nkt; ++t) {
    const int cur = t & 1;
    if (t + 1 < nkt) stage(cur ^ 1, t + 1);         // issue-early: hides under compute
    const u16* Ab = As[cur];
    const u16* Bb = Bs[cur];
#pragma unroll
    for (int ks = 0; ks < 2; ++ks) {
      bf16x8 a[4], b[4];
#pragma unroll
      for (int m = 0; m < 4; m++) a[m] = lda(Ab, m, ks);
#pragma unroll
      for (int n = 0; n < 4; n++) b[n] = ldb(Bb, n, ks);
#pragma unroll
      for (int m = 0; m < 4; m++)
#pragma unroll
        for (int n = 0; n < 4; n++)
          acc[m][n] = __builtin_amdgcn_mfma_f32_16x16x32_bf16(a[m], b[n], acc[m][n], 0, 0, 0);
    }
    __syncthreads();    // all reads of cur done; staged t+1 landed (implicit vmcnt 0)
  }

  // epilogue: D layout col = lane&15, row = (lane>>4)*4 + j
  const int rr = (lane >> 4) * 4;
  const int cc = lane & 15;
#pragma unroll
  for (int n = 0; n < 4; n++) {
    int col = n0 + wc * 64 + n * 16 + cc;
    if (col < LBL) {
      float bv = bias[col];
#pragma unroll
      for (int m = 0; m < 4; m++)
#pragma unroll
        for (int j = 0; j < 4; j++) {
          int row = m0 + wr * 64 + m * 16 + rr + j;
          C[(size_t)row * LBL + col] = acc[m][n][j] + bv;
        }
    }
  }
}

// ---------------------------------------------------------------------------
// fuse1: h1[g] = bf16( LN( gelu( s[r] + pep[t] ) ) * g1 + be1 ),  g = r*20+t
// ---------------------------------------------------------------------------
__global__ __launch_bounds__(256) void fuse1_kernel(const float* __restrict__ s,
                                                    const float* __restrict__ pep,
                                                    const float* __restrict__ g1,
                                                    const float* __restrict__ be1,
                                                    u16* __restrict__ h1) {
  __shared__ float red[8];
  int g = blockIdx.x, tid = threadIdx.x;
  int r = g / TGT, t = g - r * TGT;
  const float* sr = s + (size_t)r * HID;
  const float* pt = pep + (size_t)t * HID;
  float y[3], s1 = 0.f, s2 = 0.f;
#pragma unroll
  for (int i = 0; i < 3; i++) {
    int j = tid + i * 256;
    float x = sr[j] + pt[j];
    y[i] = gelu_tanh(x);
    s1 += y[i];
    s2 += y[i] * y[i];
  }
#pragma unroll
  for (int off = 32; off > 0; off >>= 1) {
    s1 += __shfl_down(s1, off);
    s2 += __shfl_down(s2, off);
  }
  if ((tid & 63) == 0) { red[tid >> 6] = s1; red[4 + (tid >> 6)] = s2; }
  __syncthreads();
  float mean = (red[0] + red[1] + red[2] + red[3]) * (1.0f / HID);
  float var  = (red[4] + red[5] + red[6] + red[7]) * (1.0f / HID) - mean * mean;
  float inv  = rsqrtf(var + 1e-5f);
#pragma unroll
  for (int i = 0; i < 3; i++) {
    int j = tid + i * 256;
    h1[(size_t)g * HID + j] = f2bf((y[i] - mean) * inv * g1[j] + be1[j]);
  }
}

// ---------------------------------------------------------------------------
// fuse2: h2[g] = bf16( LN( G[g] ) * g2 + be2 ) — safe in-place (G == h2)
// ---------------------------------------------------------------------------
__global__ __launch_bounds__(256) void fuse2_kernel(const u16* __restrict__ G,
                                                    const float* __restrict__ g2,
                                                    const float* __restrict__ be2,
                                                    u16* __restrict__ h2) {
  __shared__ float red[8];
  int g = blockIdx.x, tid = threadIdx.x;
  const u16* gr = G + (size_t)g * HID;
  float y[3], s1 = 0.f, s2 = 0.f;
#pragma unroll
  for (int i = 0; i < 3; i++) {
    int j = tid + i * 256;
    y[i] = bf2f(gr[j]);
    s1 += y[i];
    s2 += y[i] * y[i];
  }
#pragma unroll
  for (int off = 32; off > 0; off >>= 1) {
    s1 += __shfl_down(s1, off);
    s2 += __shfl_down(s2, off);
  }
  if ((tid & 63) == 0) { red[tid >> 6] = s1; red[4 + (tid >> 6)] = s2; }
  __syncthreads();
  float mean = (red[0] + red[1] + red[2] + red[3]) * (1.0f / HID);
  float var  = (red[4] + red[5] + red[6] + red[7]) * (1.0f / HID) - mean * mean;
  float inv  = rsqrtf(var + 1e-5f);
#pragma unroll
  for (int i = 0; i < 3; i++) {
    int j = tid + i * 256;
    h2[(size_t)g * HID + j] = f2bf((y[i] - mean) * inv * g2[j] + be2[j]);
  }
}

// ---------------------------------------------------------------------------
extern "C" void kernel_launch(void* const* d_in, const int* in_sizes, int n_in,
                              void* d_out, int out_size, void* d_ws, size_t ws_size,
                              hipStream_t stream) {
  const float* input_nodes = (const float*)d_in[0];
  const int*   pairs       = (const int*)d_in[1];
  const float* pos_emb     = (const float*)d_in[2];
  const float* W1  = (const float*)d_in[3];
  const float* b1  = (const float*)d_in[4];
  const float* g1  = (const float*)d_in[5];
  const float* be1 = (const float*)d_in[6];
  const float* W2  = (const float*)d_in[7];
  const float* b2  = (const float*)d_in[8];
  const float* g2  = (const float*)d_in[9];
  const float* be2 = (const float*)d_in[10];
  const float* Wd  = (const float*)d_in[11];
  const float* bd  = (const float*)d_in[12];
  float* out = (float*)d_out;

  char* ws = (char*)d_ws;
  u16*   WdT   = (u16*)(ws + 0);                 // 30592*768*2 = 46,989,312
  u16*   W2T   = (u16*)(ws + 46989312);          // 1,179,648
  u16*   W1lrT = (u16*)(ws + 48168960);          // 2,359,296
  u16*   A1    = (u16*)(ws + 50528256);          // 1,572,864
  float* pep   = (float*)(ws + 52101120);        // 61,440
  float* sbuf  = (float*)(ws + 52162560);        // 1,572,864
  u16*   h1    = (u16*)(ws + 53735424);          // 15,728,640
  u16*   G     = (u16*)(ws + 69464064);          // 15,728,640 -> end 85,192,704 (h2 in-place)

  // weight prep (bf16, B^T layouts)
  tconv_kernel<<<dim3(956, 24), 256, 0, stream>>>(Wd, WdT, HID, LBL, NPAD);
  tconv_kernel<<<dim3(24, 24), 256, 0, stream>>>(W2, W2T, HID, HID, HID);
  tconv_kernel<<<dim3(24, 48), 256, 0, stream>>>(W1, W1lrT, KCAT, HID, HID);
  gather_kernel<<<dim3((RPAIR * KCAT + 255) / 256), 256, 0, stream>>>(input_nodes, pairs, A1);
  peproj_kernel<<<dim3(TGT), 256, 0, stream>>>(pos_emb, W1, b1, pep);

  // layer 1: s = [lh|rh] @ W1[0:1536]   (512 x 768)
  gemm_bt<0><<<dim3(6, 4), 256, 0, stream>>>(A1, W1lrT, nullptr, sbuf, nullptr, HID, KCAT);
  fuse1_kernel<<<dim3(ROWS), 256, 0, stream>>>(sbuf, pep, g1, be1, h1);

  // layer 2: G = gelu(h1 @ W2 + b2); h2 = LN(G) in-place
  gemm_bt<1><<<dim3(6, 80), 256, 0, stream>>>(h1, W2T, b2, nullptr, G, HID, HID);
  fuse2_kernel<<<dim3(ROWS), 256, 0, stream>>>(G, g2, be2, G);

  // head: out = h2 @ Wd + bd   (10240 x 30522), 2-phase dbuf BK=64
  gemm128_head<<<dim3(19120), 256, 0, stream>>>(G, WdT, bd, out);
}

// Round 5
// 1181.358 us; speedup vs baseline: 1.0968x; 1.0893x over previous
//
#include <hip/hip_runtime.h>
#include <stdint.h>
#include <math.h>

typedef unsigned short u16;
typedef unsigned int u32;

#define HID   768
#define TGT   20
#define LBL   30522
#define RPAIR 512
#define ROWS  10240          // RPAIR * TGT
#define KCAT  1536           // 2*HID (lh|rh)
#define NPAD2 30720          // 120 * 256  (LBL padded to 256-tile multiple)

typedef float  f32x4  __attribute__((ext_vector_type(4)));
typedef __bf16 bf16x8 __attribute__((ext_vector_type(8)));

__device__ __forceinline__ u16 f2bf(float f) {
  u32 u = __float_as_uint(f);
  u += 0x7fffu + ((u >> 16) & 1u);          // RNE
  return (u16)(u >> 16);
}
__device__ __forceinline__ float bf2f(u16 h) {
  return __uint_as_float(((u32)h) << 16);
}
__device__ __forceinline__ float gelu_tanh(float x) {
  float x3 = x * x * x;
  float t = tanhf(0.7978845608028654f * (x + 0.044715f * x3));
  return 0.5f * x * (1.0f + t);
}

// async global->LDS, 16B per lane; lds dst wave-uniform base (HW adds lane*16)
__device__ __forceinline__ void async16(u16* lds, const u16* g) {
  __builtin_amdgcn_global_load_lds(
      (__attribute__((address_space(1))) void*)const_cast<u16*>(g),
      (__attribute__((address_space(3))) void*)lds,
      16, 0, 0);
}

#define BARRIER() do { asm volatile("" ::: "memory"); __builtin_amdgcn_s_barrier(); asm volatile("" ::: "memory"); } while (0)
#define VMWAIT8() do { asm volatile("s_waitcnt vmcnt(8)" ::: "memory"); __builtin_amdgcn_sched_barrier(0); } while (0)
#define VMWAIT0() do { asm volatile("s_waitcnt vmcnt(0)" ::: "memory"); __builtin_amdgcn_sched_barrier(0); } while (0)

// ---------------------------------------------------------------------------
// Transpose + f32->bf16:  B[K][N] f32  ->  Bt[Npad][K] bf16 (pad rows zeroed)
// ---------------------------------------------------------------------------
__global__ __launch_bounds__(256) void tconv_kernel(const float* __restrict__ B,
                                                    u16* __restrict__ Bt,
                                                    int K, int N, int Npad) {
  __shared__ u16 tile[32][34];
  int n0 = blockIdx.x * 32, k0 = blockIdx.y * 32;
  int tx = threadIdx.x & 31, ty = threadIdx.x >> 5;
#pragma unroll
  for (int i = 0; i < 4; i++) {
    int kk = ty + i * 8;
    int k = k0 + kk, n = n0 + tx;
    float v = (k < K && n < N) ? B[(size_t)k * N + n] : 0.0f;
    tile[kk][tx] = f2bf(v);
  }
  __syncthreads();
#pragma unroll
  for (int i = 0; i < 4; i++) {
    int nn = ty + i * 8;
    int n = n0 + nn, k = k0 + tx;
    if (n < Npad && k < K) Bt[(size_t)n * K + k] = tile[tx][nn];
  }
}

// ---------------------------------------------------------------------------
// Gather pair rows -> A1[512][1536] bf16
// ---------------------------------------------------------------------------
__global__ __launch_bounds__(256) void gather_kernel(const float* __restrict__ nodes,
                                                     const int* __restrict__ p32,
                                                     u16* __restrict__ A1) {
  int idx = blockIdx.x * 256 + threadIdx.x;
  if (idx >= RPAIR * KCAT) return;
  bool is64 = ((p32[1] | p32[3] | p32[5] | p32[7] | p32[9] | p32[11] | p32[13] | p32[15]) == 0);
  int r = idx / KCAT, c = idx - r * KCAT;
  int b = r >> 7, p = r & 127;
  int which = (c >= HID) ? 1 : 0;
  int cc = which ? (c - HID) : c;          // HID=768 is NOT pow2
  int slot = (b * 128 + p) * 2 + which;
  int node = (is64 ? p32[slot * 2] : p32[slot]) + 1;
  float v = nodes[((size_t)(b * 512 + node)) * HID + cc];
  A1[idx] = f2bf(v);
}

// ---------------------------------------------------------------------------
// pe_proj[t][j] = pos_emb[t] @ W1[1536:2304] + b1     (20 x 768)
// ---------------------------------------------------------------------------
__global__ __launch_bounds__(256) void peproj_kernel(const float* __restrict__ pos_emb,
                                                     const float* __restrict__ W1,
                                                     const float* __restrict__ b1,
                                                     float* __restrict__ pep) {
  __shared__ float pe[HID];
  int t = blockIdx.x, tid = threadIdx.x;
  for (int i = tid; i < HID; i += 256) pe[i] = pos_emb[t * HID + i];
  __syncthreads();
  float acc0 = 0.f, acc1 = 0.f, acc2 = 0.f;
  const float* Wp = W1 + (size_t)KCAT * HID;
  for (int k = 0; k < HID; k++) {
    float p = pe[k];
    const float* wr = Wp + (size_t)k * HID;
    acc0 = fmaf(p, wr[tid], acc0);
    acc1 = fmaf(p, wr[tid + 256], acc1);
    acc2 = fmaf(p, wr[tid + 512], acc2);
  }
  pep[t * HID + tid]       = acc0 + b1[tid];
  pep[t * HID + tid + 256] = acc1 + b1[tid + 256];
  pep[t * HID + tid + 512] = acc2 + b1[tid + 512];
}

// ---------------------------------------------------------------------------
// 128x128 MFMA GEMM (m97 structure, BK=32) for the two small layers
// EPI 0: C f32 plain   EPI 1: C bf16 = bf16(gelu(acc+bias))
// ---------------------------------------------------------------------------
template <int EPI>
__global__ __launch_bounds__(256) void gemm_bt(const u16* __restrict__ A,
                                               const u16* __restrict__ Bt,
                                               const float* __restrict__ bias,
                                               float* __restrict__ Cf,
                                               u16* __restrict__ Cb,
                                               int N, int K) {
  __shared__ __align__(16) u16 As[128 * 32];
  __shared__ __align__(16) u16 Bs[128 * 32];
  const int tid  = threadIdx.x;
  const int lane = tid & 63;
  const int w    = tid >> 6;
  const int wr   = w >> 1, wc = w & 1;
  const int m0 = blockIdx.y * 128;
  const int n0 = blockIdx.x * 128;

  f32x4 acc[4][4];
  const f32x4 fzero = {0.f, 0.f, 0.f, 0.f};
#pragma unroll
  for (int m = 0; m < 4; m++)
#pragma unroll
    for (int n = 0; n < 4; n++) acc[m][n] = fzero;

  const int srow = lane >> 2;
  const int scol = (lane & 3) * 8;
  const int nkt = K >> 5;

  for (int kt = 0; kt < nkt; ++kt) {
    const int k0 = kt << 5;
#pragma unroll
    for (int j = 0; j < 2; j++) {
      int rbase = w * 32 + j * 16;
      async16(&As[rbase * 32], A + (size_t)(m0 + rbase + srow) * K + k0 + scol);
      async16(&Bs[rbase * 32], Bt + (size_t)(n0 + rbase + srow) * K + k0 + scol);
    }
    asm volatile("s_waitcnt vmcnt(0)" ::: "memory");
    __syncthreads();

    bf16x8 a[4], b[4];
    const int kk = (lane >> 4) * 8;
#pragma unroll
    for (int m = 0; m < 4; m++)
      a[m] = *reinterpret_cast<const bf16x8*>(&As[(wr * 64 + m * 16 + (lane & 15)) * 32 + kk]);
#pragma unroll
    for (int n = 0; n < 4; n++)
      b[n] = *reinterpret_cast<const bf16x8*>(&Bs[(wc * 64 + n * 16 + (lane & 15)) * 32 + kk]);
#pragma unroll
    for (int m = 0; m < 4; m++)
#pragma unroll
      for (int n = 0; n < 4; n++)
        acc[m][n] = __builtin_amdgcn_mfma_f32_16x16x32_bf16(a[m], b[n], acc[m][n], 0, 0, 0);
    __syncthreads();
  }

  const int rr = (lane >> 4) * 4;
  const int cc = lane & 15;
#pragma unroll
  for (int m = 0; m < 4; m++) {
#pragma unroll
    for (int n = 0; n < 4; n++) {
      int col = n0 + wc * 64 + n * 16 + cc;
#pragma unroll
      for (int j = 0; j < 4; j++) {
        int row = m0 + wr * 64 + m * 16 + rr + j;
        float v = acc[m][n][j];
        if (EPI == 0) {
          Cf[(size_t)row * N + col] = v;
        } else {
          v = gelu_tanh(v + bias[col]);
          Cb[(size_t)row * N + col] = f2bf(v);
        }
      }
    }
  }
}

// ---------------------------------------------------------------------------
// Head GEMM, persistent-stream version.
// 256x256 tile, BK=64, 8 waves (2m x 4n, wave=128x64), dbuf LDS 128 KiB.
// Grid = 256 blocks; XCD x = bid&7 owns m-tiles [5x,5x+5); its 32 blocks split
// the XCD's 600 (m,n) tiles into contiguous 18-19-tile chunks (n-major) ->
// ONE flat stream of ~225 BK-64 iterations per block; pipeline fills once.
// Per iteration q:  issue stage(q+1) [8 gload_lds/wave] ; s_waitcnt vmcnt(8)
//   (retires stage(q), keeps stage(q+1) in flight) ; s_barrier ;
//   ds_read frags (chunk-XOR swizzled) ; 64 MFMA (setprio 1) ; s_barrier.
// Epilogue at kt==11: 128 dword stores/thread (+bias), acc reset; the next
// vmcnt(8) over-waits through the stores (accepted, once per 12 iters).
// ---------------------------------------------------------------------------
__global__ __launch_bounds__(512, 2) void gemm256_stream(const u16* __restrict__ A,
                                                         const u16* __restrict__ B,
                                                         const float* __restrict__ bias,
                                                         float* __restrict__ C) {
  __shared__ __align__(16) u16 As[2][256 * 64];
  __shared__ __align__(16) u16 Bs[2][256 * 64];
  const int tid  = threadIdx.x;
  const int lane = tid & 63;
  const int wid  = tid >> 6;           // 0..7
  const int wm   = wid >> 2;           // 0..1
  const int wn   = wid & 3;            // 0..3

  const int x  = blockIdx.x & 7;       // XCD guess
  const int jb = blockIdx.x >> 3;      // 0..31
  const int t0 = (600 * jb) >> 5;      // 18.75 per block
  const int t1 = (600 * (jb + 1)) >> 5;
  const int Q  = (t1 - t0) * 12;       // BK-64 iterations in this block's stream

  f32x4 acc[8][4];
  const f32x4 fzero = {0.f, 0.f, 0.f, 0.f};
#pragma unroll
  for (int mi = 0; mi < 8; mi++)
#pragma unroll
    for (int ni = 0; ni < 4; ni++) acc[mi][ni] = fzero;

  // staging geometry: lane covers row sl_r of an 8-row stripe, pre-swizzled chunk
  const int sl_r = lane >> 3;                   // 0..7
  const int sl_c = ((lane & 7) ^ sl_r) * 8;     // 16B-chunk XOR swizzle (global side)

  auto stage = [&](int q) {
    int tt = t0 + q / 12;
    int kt = q - (q / 12) * 12;
    int mt = 5 * x + tt / 120;
    int nt = tt - (tt / 120) * 120;
    const int k0 = kt * 64;
    u16* Ab = As[q & 1];
    u16* Bb = Bs[q & 1];
    const u16* Ag = A + (size_t)(mt * 256) * 768 + k0;
    const u16* Bg = B + (size_t)(nt * 256) * 768 + k0;
#pragma unroll
    for (int jj = 0; jj < 4; jj++) {
      int rbase = wid * 32 + jj * 8;            // wave-uniform, 8 rows per instr
      async16(Ab + rbase * 64, Ag + (size_t)(rbase + sl_r) * 768 + sl_c);
      async16(Bb + rbase * 64, Bg + (size_t)(rbase + sl_r) * 768 + sl_c);
    }
  };
  // swizzled ds_read of one bf16x8 fragment
  auto lda = [&](const u16* buf, int mi, int ks) -> bf16x8 {
    int row = wm * 128 + mi * 16 + (lane & 15);
    int kch = ks * 4 + (lane >> 4);
    return *reinterpret_cast<const bf16x8*>(&buf[row * 64 + ((kch ^ (row & 7)) << 3)]);
  };
  auto ldb = [&](const u16* buf, int ni, int ks) -> bf16x8 {
    int row = wn * 64 + ni * 16 + (lane & 15);
    int kch = ks * 4 + (lane >> 4);
    return *reinterpret_cast<const bf16x8*>(&buf[row * 64 + ((kch ^ (row & 7)) << 3)]);
  };

  const int rr  = (lane >> 4) * 4;
  const int ccl = lane & 15;

  stage(0);                                     // 8 outstanding
  for (int q = 0; q < Q; ++q) {
    if (q + 1 < Q) { stage(q + 1); VMWAIT8(); } // S(q) landed, S(q+1) in flight
    else          { VMWAIT0(); }
    BARRIER();                                  // all waves' S(q) visible

    const u16* Ab = As[q & 1];
    const u16* Bb = Bs[q & 1];
#pragma unroll
    for (int ks = 0; ks < 2; ++ks) {
      bf16x8 aF[8], bF[4];
#pragma unroll
      for (int mi = 0; mi < 8; ++mi) aF[mi] = lda(Ab, mi, ks);
#pragma unroll
      for (int ni = 0; ni < 4; ++ni) bF[ni] = ldb(Bb, ni, ks);
      __builtin_amdgcn_s_setprio(1);
#pragma unroll
      for (int mi = 0; mi < 8; ++mi)
#pragma unroll
        for (int ni = 0; ni < 4; ++ni)
          acc[mi][ni] = __builtin_amdgcn_mfma_f32_16x16x32_bf16(aF[mi], bF[ni], acc[mi][ni], 0, 0, 0);
      __builtin_amdgcn_s_setprio(0);
    }

    int kt = q - (q / 12) * 12;
    if (kt == 11) {
      // epilogue for tile q/12
      int tt = t0 + q / 12;
      int mt = 5 * x + tt / 120;
      int nt = tt - (tt / 120) * 120;
      int r0 = mt * 256 + wm * 128;
      int c0 = nt * 256 + wn * 64;
#pragma unroll
      for (int ni = 0; ni < 4; ++ni) {
        int col = c0 + ni * 16 + ccl;
        if (col < LBL) {
          float bv = bias[col];
#pragma unroll
          for (int mi = 0; mi < 8; ++mi)
#pragma unroll
            for (int j = 0; j < 4; ++j)
              C[(size_t)(r0 + mi * 16 + rr + j) * LBL + col] = acc[mi][ni][j] + bv;
        }
      }
#pragma unroll
      for (int mi = 0; mi < 8; mi++)
#pragma unroll
        for (int ni = 0; ni < 4; ni++) acc[mi][ni] = fzero;
    }
    BARRIER();                                  // all reads of buf[q&1] done
  }
}

// ---------------------------------------------------------------------------
// fuse1: h1[g] = bf16( LN( gelu( s[r] + pep[t] ) ) * g1 + be1 ),  g = r*20+t
// ---------------------------------------------------------------------------
__global__ __launch_bounds__(256) void fuse1_kernel(const float* __restrict__ s,
                                                    const float* __restrict__ pep,
                                                    const float* __restrict__ g1,
                                                    const float* __restrict__ be1,
                                                    u16* __restrict__ h1) {
  __shared__ float red[8];
  int g = blockIdx.x, tid = threadIdx.x;
  int r = g / TGT, t = g - r * TGT;
  const float* sr = s + (size_t)r * HID;
  const float* pt = pep + (size_t)t * HID;
  float y[3], s1 = 0.f, s2 = 0.f;
#pragma unroll
  for (int i = 0; i < 3; i++) {
    int j = tid + i * 256;
    float x = sr[j] + pt[j];
    y[i] = gelu_tanh(x);
    s1 += y[i];
    s2 += y[i] * y[i];
  }
#pragma unroll
  for (int off = 32; off > 0; off >>= 1) {
    s1 += __shfl_down(s1, off);
    s2 += __shfl_down(s2, off);
  }
  if ((tid & 63) == 0) { red[tid >> 6] = s1; red[4 + (tid >> 6)] = s2; }
  __syncthreads();
  float mean = (red[0] + red[1] + red[2] + red[3]) * (1.0f / HID);
  float var  = (red[4] + red[5] + red[6] + red[7]) * (1.0f / HID) - mean * mean;
  float inv  = rsqrtf(var + 1e-5f);
#pragma unroll
  for (int i = 0; i < 3; i++) {
    int j = tid + i * 256;
    h1[(size_t)g * HID + j] = f2bf((y[i] - mean) * inv * g1[j] + be1[j]);
  }
}

// ---------------------------------------------------------------------------
// fuse2: h2[g] = bf16( LN( G[g] ) * g2 + be2 ) — safe in-place (G == h2)
// ---------------------------------------------------------------------------
__global__ __launch_bounds__(256) void fuse2_kernel(const u16* __restrict__ G,
                                                    const float* __restrict__ g2,
                                                    const float* __restrict__ be2,
                                                    u16* __restrict__ h2) {
  __shared__ float red[8];
  int g = blockIdx.x, tid = threadIdx.x;
  const u16* gr = G + (size_t)g * HID;
  float y[3], s1 = 0.f, s2 = 0.f;
#pragma unroll
  for (int i = 0; i < 3; i++) {
    int j = tid + i * 256;
    y[i] = bf2f(gr[j]);
    s1 += y[i];
    s2 += y[i] * y[i];
  }
#pragma unroll
  for (int off = 32; off > 0; off >>= 1) {
    s1 += __shfl_down(s1, off);
    s2 += __shfl_down(s2, off);
  }
  if ((tid & 63) == 0) { red[tid >> 6] = s1; red[4 + (tid >> 6)] = s2; }
  __syncthreads();
  float mean = (red[0] + red[1] + red[2] + red[3]) * (1.0f / HID);
  float var  = (red[4] + red[5] + red[6] + red[7]) * (1.0f / HID) - mean * mean;
  float inv  = rsqrtf(var + 1e-5f);
#pragma unroll
  for (int i = 0; i < 3; i++) {
    int j = tid + i * 256;
    h2[(size_t)g * HID + j] = f2bf((y[i] - mean) * inv * g2[j] + be2[j]);
  }
}

// ---------------------------------------------------------------------------
extern "C" void kernel_launch(void* const* d_in, const int* in_sizes, int n_in,
                              void* d_out, int out_size, void* d_ws, size_t ws_size,
                              hipStream_t stream) {
  const float* input_nodes = (const float*)d_in[0];
  const int*   pairs       = (const int*)d_in[1];
  const float* pos_emb     = (const float*)d_in[2];
  const float* W1  = (const float*)d_in[3];
  const float* b1  = (const float*)d_in[4];
  const float* g1  = (const float*)d_in[5];
  const float* be1 = (const float*)d_in[6];
  const float* W2  = (const float*)d_in[7];
  const float* b2  = (const float*)d_in[8];
  const float* g2  = (const float*)d_in[9];
  const float* be2 = (const float*)d_in[10];
  const float* Wd  = (const float*)d_in[11];
  const float* bd  = (const float*)d_in[12];
  float* out = (float*)d_out;

  char* ws = (char*)d_ws;
  u16*   WdT   = (u16*)(ws + 0);                 // 30720*768*2 = 47,185,920
  u16*   W2T   = (u16*)(ws + 47185920);          // 1,179,648
  u16*   W1lrT = (u16*)(ws + 48365568);          // 2,359,296
  u16*   A1    = (u16*)(ws + 50724864);          // 1,572,864
  float* pep   = (float*)(ws + 52297728);        // 61,440
  float* sbuf  = (float*)(ws + 52359168);        // 1,572,864
  u16*   h1    = (u16*)(ws + 53932032);          // 15,728,640
  u16*   G     = (u16*)(ws + 69660672);          // 15,728,640 -> end 85,389,312 (h2 in-place)

  // weight prep (bf16, B^T layouts)
  tconv_kernel<<<dim3(960, 24), 256, 0, stream>>>(Wd, WdT, HID, LBL, NPAD2);
  tconv_kernel<<<dim3(24, 24), 256, 0, stream>>>(W2, W2T, HID, HID, HID);
  tconv_kernel<<<dim3(24, 48), 256, 0, stream>>>(W1, W1lrT, KCAT, HID, HID);
  gather_kernel<<<dim3((RPAIR * KCAT + 255) / 256), 256, 0, stream>>>(input_nodes, pairs, A1);
  peproj_kernel<<<dim3(TGT), 256, 0, stream>>>(pos_emb, W1, b1, pep);

  // layer 1: s = [lh|rh] @ W1[0:1536]   (512 x 768)
  gemm_bt<0><<<dim3(6, 4), 256, 0, stream>>>(A1, W1lrT, nullptr, sbuf, nullptr, HID, KCAT);
  fuse1_kernel<<<dim3(ROWS), 256, 0, stream>>>(sbuf, pep, g1, be1, h1);

  // layer 2: G = gelu(h1 @ W2 + b2); h2 = LN(G) in-place
  gemm_bt<1><<<dim3(6, 80), 256, 0, stream>>>(h1, W2T, b2, nullptr, G, HID, HID);
  fuse2_kernel<<<dim3(ROWS), 256, 0, stream>>>(G, g2, be2, G);

  // head: out = h2 @ Wd + bd   (10240 x 30522), persistent 256^2 stream
  gemm256_stream<<<dim3(256), 512, 0, stream>>>(G, WdT, bd, out);
}